// Round 14
// baseline (61.620 us; speedup 1.0000x reference)
//
#include <hip/hip_runtime.h>

#define NB 128
#define NTOK 201
#define EW 210   // u-slot holding the att-col-0 (e-column) weight

// Publish LDS writes across a barrier WITHOUT draining vmcnt.
__device__ __forceinline__ void lds_barrier() {
    asm volatile("s_waitcnt lgkmcnt(0)" ::: "memory");
    __builtin_amdgcn_s_barrier();
}

// u^T <- u^T * att_e[l], l = 10..0, u0 = row 0 of att_e[11].
// 256 threads = NC row-classes x (256/NC) lanes. Heavy (M=197): NC=4 (LSH=6).
// Light (M=99): NC=8 (LSH=5) -> 13 row-iters/lane instead of 25, 84% active.
// Padded-col space p = xcol-(lo-3), valid [3,M+2), e-weight at u[EW].
// Class rc start col C_rc = lo - ((b+2lo-1+rc)&3) is 16B-aligned (row stride
// NC*201 === 0 mod 4); per-class col shift undone in the reduce. Rows r >= M
// clamp in-class (r-NC), auto-masked by zero weight u[r+2]. e-column folded
// into the vector loop: lane g==W4 uses quad base e-sel, extracts comp sel.
template<int M, int LSH>
__device__ __forceinline__ void chain_nc(
    const float* __restrict__ xb, float* __restrict__ out,
    const int e, const int b, const int lo,
    float* u, float (*part)[212], float* rv, int* rix)
{
    constexpr int NC = 256 >> LSH;       // row classes (4 / 8)
    constexpr int W4 = (M + 5) / 4;      // active float4 col-groups (50 / 26)
    constexpr int NK = (M + NC - 1) / NC; // row-iters per lane (50 / 13)

    const int tid = threadIdx.x;
    const int g   = tid & ((1 << LSH) - 1);
    const int rc  = tid >> LSH;          // row class 0..NC-1

    const size_t plane = (size_t)NTOK * NTOK;
    const float* L11 = xb + (size_t)(11 * NB) * plane + (size_t)e * NTOK;

    const int trc = (b + 2 * lo - 1 + rc) & 3;
    const int C   = lo - trc;            // 16B-aligned start col for this class
    const int sel = (b + lo - 1 + rc + e) & 3;  // col e's comp in lane-W4 quads
    const int col0 = (g < W4) ? (C + 4 * g) : (e - sel);

    // init u: zeros (clamp slots must stay 0), then valid slots
    if (tid < 212) u[tid] = 0.f;
    __syncthreads();
    if (tid >= 3 && tid < M + 2) u[tid] = L11[lo - 3 + tid];
    if (tid == EW)               u[tid] = L11[e];
    __syncthreads();

    const size_t rstep = (size_t)(NC * NTOK);
    const float* A = xb + (size_t)(10 * NB) * plane;

    for (int l = 10; l >= 0; --l) {
        if (g <= W4) {
            float4 acc = make_float4(0.f, 0.f, 0.f, 0.f);
            float shead = 0.f;
            if (rc == 0) {               // att row 0 = x row e (class 0 only)
                const float hw = u[EW];
                if (g < W4) {            // scalar loads: head row not in class
                    const float* hp = A + (size_t)e * NTOK + col0;
                    acc.x = hw * hp[0]; acc.y = hw * hp[1];
                    acc.z = hw * hp[2]; acc.w = hw * hp[3];
                } else {
                    shead = hw * A[(size_t)e * NTOK + e];
                }
            }
            const float* rp = A + (size_t)(lo - 1 + rc) * NTOK + col0;
            #pragma unroll
            for (int k = 0; k < NK - 1; ++k) {
                const float wt = u[rc + 2 + NC * k];
                const float4 a = *(const float4*)(rp + rstep * k);
                acc.x += wt * a.x; acc.y += wt * a.y;
                acc.z += wt * a.z; acc.w += wt * a.w;
            }
            {   // tail row, in-class clamp for r >= M (zero weight there)
                constexpr int k = NK - 1;
                const int r = rc + NC * k;
                const float wt = u[r + 2];
                const float4 a = *(const float4*)(rp + rstep * k
                                                  - ((r >= M) ? rstep : 0));
                acc.x += wt * a.x; acc.y += wt * a.y;
                acc.z += wt * a.z; acc.w += wt * a.w;
            }
            if (g < W4) {
                *(float4*)&part[rc][4 * g] = acc;
            } else {
                const float se = (sel == 0) ? acc.x :
                                 (sel == 1) ? acc.y :
                                 (sel == 2) ? acc.z : acc.w;
                part[rc][EW] = se + shead;
            }
        }
        lds_barrier();                   // publish part
        // reduce NC partials -> u (reads part, writes u: disjoint arrays)
        if (tid >= 3 && tid < M + 2) {
            float s = 0.f;
            #pragma unroll
            for (int q = 0; q < NC; ++q) {
                const int tq = (b + 2 * lo - 1 + q) & 3;
                s += part[q][tid - 3 + tq];   // undo per-class col shift
            }
            u[tid] = s;
        } else if (tid == EW) {
            float s = 0.f;
            #pragma unroll
            for (int q = 0; q < NC; ++q) s += part[q][EW];
            u[EW] = s;
        }
        lds_barrier();                   // publish u / guard part reuse
        A -= (size_t)NB * plane;
    }

    // max + argmax over p in [3, M+2); p ascending == att-col ascending
    {
        float v = -INFINITY; int idx = 0x7fffffff;
        if (tid >= 3 && tid < M + 2) { v = u[tid]; idx = tid; }
        rv[tid] = v; rix[tid] = idx;
    }
    __syncthreads();
    for (int s = 128; s > 0; s >>= 1) {
        if (tid < s) {
            const float v2 = rv[tid + s]; const int i2 = rix[tid + s];
            if (v2 > rv[tid] || (v2 == rv[tid] && i2 < rix[tid])) {
                rv[tid] = v2; rix[tid] = i2;
            }
        }
        __syncthreads();
    }
    if (tid == 0) {
        out[e * NB + b]       = rv[0];
        out[640 + e * NB + b] = (float)(lo - 3 + rix[0]);   // = (j-1) + lo
    }
}

// bid = 128*e + b => bid%8 = b%8: all 5 chains of a batch on the SAME XCD
// (shared L2 dedups overlapping plane reads). 640 small blocks -> ~2.5
// independent chains/CU whose phases interleave (MLP across blocks).
__global__ __launch_bounds__(256, 4) void part_att_kernel(
    const float* __restrict__ x, float* __restrict__ out)
{
    __shared__ float u[212];
    __shared__ float part[8][212];
    __shared__ float rv[256];
    __shared__ int   rix[256];

    const int bid = blockIdx.x;
    const int e   = bid >> 7;
    const int b   = bid & 127;
    const float* xb = x + (size_t)b * ((size_t)NTOK * NTOK);

    if (e < 2) {
        chain_nc<197, 6>(xb, out, e, b, 5, u, part, rv, rix);   // 4 classes x 64
    } else {
        const int lo = (e == 2) ? 5 : (e == 3) ? 54 : 103;
        chain_nc<99, 5>(xb, out, e, b, lo, u, part, rv, rix);   // 8 classes x 32
    }
}

extern "C" void kernel_launch(void* const* d_in, const int* in_sizes, int n_in,
                              void* d_out, int out_size, void* d_ws, size_t ws_size,
                              hipStream_t stream) {
    (void)in_sizes; (void)n_in; (void)d_ws; (void)ws_size; (void)out_size;
    const float* x = (const float*)d_in[0];
    float* out = (float*)d_out;
    part_att_kernel<<<dim3(640), dim3(256), 0, stream>>>(x, out);
}